// Round 2
// baseline (995.215 us; speedup 1.0000x reference)
//
#include <hip/hip_runtime.h>

// NNMF fused kernel: B=8192, NIN=3072, NOUT=512, 5 iterations.
// Row-independence => single persistent main kernel, all 5 iterations fused.
// W pre-shuffled into MFMA-fragment order (2 orientations) in d_ws; x pre-normalized
// to bf16 in d_ws. Main: 256 blocks x 512 thr, 32 rows/block, KT=128 k-steps.
// R1 fix: h kept in fp32 REGISTERS across iterations (C-layout); h_lds bf16 is
// only the Phase-A MFMA operand cache. Removes the dominant 0.2%/iter h-round error.

#define NIN 3072
#define NOUT 512
#define BT 32

using bf16x8 = __attribute__((ext_vector_type(8))) short;
using f32x4  = __attribute__((ext_vector_type(4))) float;

__device__ __forceinline__ unsigned short f2bf(float f) {
    unsigned int u = __builtin_bit_cast(unsigned int, f);
    return (unsigned short)((u + 0x7fffu + ((u >> 16) & 1u)) >> 16);  // RNE
}
__device__ __forceinline__ float bf2f(unsigned short s) {
    unsigned int u = ((unsigned int)s) << 16;
    return __builtin_bit_cast(float, u);
}

// ---------------------------------------------------------------------------
// prep_w: shuffle W (fp32 [512][3072]) into MFMA-frag-native bf16 buffers.
// W2 (for t = r @ W^T, contract over k): frag (kcg in [0,96), nt in [0,32)):
//   W2[((kcg*32+nt)*64 + l)*8 + j] = W[nt*16 + (l&15)][kcg*32 + (l>>4)*8 + j]
// W1 (for denom = h @ W, contract over n): frag (ktg in [0,192), nc in [0,16)):
//   W1[((ktg*16+nc)*64 + l)*8 + j] = W[nc*32 + (l>>4)*8 + j][ktg*16 + (l&15)]
// ---------------------------------------------------------------------------
__global__ void prep_w(const float* __restrict__ W,
                       unsigned short* __restrict__ W1,
                       unsigned short* __restrict__ W2) {
    int t = blockIdx.x * 256 + threadIdx.x;   // 0 .. 393215
    const int half = 196608;
    if (t < half) {
        int f = t >> 6, l = t & 63;
        int kcg = f >> 5, nt = f & 31;
        int n = nt * 16 + (l & 15);
        int k = kcg * 32 + ((l >> 4) << 3);
        unsigned short* dst = W2 + (size_t)t * 8;
        const float* src = W + (size_t)n * NIN + k;
        #pragma unroll
        for (int j = 0; j < 8; ++j) dst[j] = f2bf(src[j]);
    } else {
        int u = t - half;
        int f = u >> 6, l = u & 63;
        int ktg = f >> 4, nc = f & 15;
        int k = ktg * 16 + (l & 15);
        int nb = nc * 32 + ((l >> 4) << 3);
        unsigned short* dst = W1 + (size_t)u * 8;
        #pragma unroll
        for (int j = 0; j < 8; ++j) dst[j] = f2bf(W[(size_t)(nb + j) * NIN + k]);
    }
}

// ---------------------------------------------------------------------------
// prep_x: per-row normalize x and store bf16. X2[b][k] = bf16(x[b][k]/(sum_k x + eps))
// ---------------------------------------------------------------------------
__global__ void prep_x(const float* __restrict__ x, unsigned short* __restrict__ X2) {
    int b = blockIdx.x;
    int t = threadIdx.x;                      // 256 threads
    const float4* r4 = reinterpret_cast<const float4*>(x + (size_t)b * NIN);
    float s = 0.f;
    float4 v0 = r4[t], v1 = r4[t + 256], v2 = r4[t + 512];
    s = v0.x + v0.y + v0.z + v0.w + v1.x + v1.y + v1.z + v1.w + v2.x + v2.y + v2.z + v2.w;
    #pragma unroll
    for (int off = 32; off > 0; off >>= 1) s += __shfl_down(s, off, 64);
    __shared__ float wsum[4];
    int w = t >> 6, l = t & 63;
    if (l == 0) wsum[w] = s;
    __syncthreads();
    float inv = 1.0f / (wsum[0] + wsum[1] + wsum[2] + wsum[3] + 1e-20f);
    unsigned short* orow = X2 + (size_t)b * NIN;
    #pragma unroll
    for (int c = 0; c < 3; ++c) {
        float4 v = (c == 0) ? v0 : (c == 1) ? v1 : v2;
        ushort4 o;
        o.x = f2bf(v.x * inv); o.y = f2bf(v.y * inv);
        o.z = f2bf(v.z * inv); o.w = f2bf(v.w * inv);
        *reinterpret_cast<ushort4*>(orow + (t + c * 256) * 4) = o;
    }
}

// ---------------------------------------------------------------------------
// Main fused kernel. 256 blocks x 512 threads (8 waves). Block owns 32 rows.
// Per iteration: sweep NIN in 24 steps of KT=128.
//  Phase A (wave w -> k-cols w*16..w*16+15): denom = h @ W (K=512) from
//    h_lds A-frags + W1 global B-frags; then r = x/(denom+eps) -> r_lds (bf16).
//  Phase B (wave w -> n-cols w*64..w*64+63): t += r @ W^T (K=128) from
//    r_lds A-frags + W2 global B-frags, fp32 accum in regs (C-layout).
//  Boundary: h_new = normalize(h*(1+t)) in fp32 registers; bf16 copy to h_lds
//  for next iteration's operands; fp32 store on the last iteration.
// ---------------------------------------------------------------------------
__global__ __launch_bounds__(512, 2) void nnmf_main(
    const unsigned short* __restrict__ X2,
    const unsigned short* __restrict__ W1,
    const unsigned short* __restrict__ W2,
    const float* __restrict__ h_init,
    float* __restrict__ out)
{
    __shared__ unsigned short h_lds[32 * 520];   // pad 512->520: row stride 1040B = 4 banks shift
    __shared__ unsigned short x_lds[32 * 136];   // pad 128->136
    __shared__ unsigned short r_lds[32 * 136];
    __shared__ float red[8][32];

    const int tid = threadIdx.x;
    const int w  = tid >> 6;        // wave 0..7
    const int l  = tid & 63;
    const int lo = l & 15;
    const int hi = l >> 4;          // 0..3
    const int b0 = blockIdx.x * BT;

    // init h_lds from h_initial (same value for every row)
    for (int idx = tid; idx < 32 * 512; idx += 512) {
        int r = idx >> 9, c = idx & 511;
        h_lds[r * 520 + c] = f2bf(h_init[c]);
    }

    // fp32 h in registers, C-layout: row=m*16+hi*4+i, col=w*64+nt*16+lo
    float h_reg[2][4][4];
    #pragma unroll
    for (int nt = 0; nt < 4; ++nt) {
        float hv = h_init[w * 64 + nt * 16 + lo];
        #pragma unroll
        for (int m = 0; m < 2; ++m)
            #pragma unroll
            for (int i = 0; i < 4; ++i)
                h_reg[m][nt][i] = hv;
    }

    // x staging: thread -> (row, 16B chunk)
    const int xrow = tid >> 4, xcc = tid & 15;
    const uint4* xg = reinterpret_cast<const uint4*>(X2 + (size_t)(b0 + xrow) * NIN + xcc * 8);
    unsigned short* xdst = &x_lds[xrow * 136 + xcc * 8];

    // W frag base pointers (element offsets)
    const unsigned short* w1base = W1 + ((size_t)(w * 16) * 64 + l) * 8;  // +s*65536, +nc*512
    const unsigned short* w2base = W2 + ((size_t)(w * 4) * 64 + l) * 8;   // +s*65536, +kc*16384, +nt*512

    f32x4 tacc[2][4];

    for (int it = 0; it < 5; ++it) {
        #pragma unroll
        for (int m = 0; m < 2; ++m)
            #pragma unroll
            for (int nt = 0; nt < 4; ++nt)
                tacc[m][nt] = (f32x4){0.f, 0.f, 0.f, 0.f};

        for (int s = 0; s < 24; ++s) {
            // ---- stage x tile [32][128]
            uint4 xv = xg[s * 16];
            *reinterpret_cast<uint4*>(xdst) = xv;
            __syncthreads();

            // ---- Phase A: denom tiles (m=0,1), cols w*16+lo
            f32x4 a0a = {0,0,0,0}, a0b = {0,0,0,0}, a1a = {0,0,0,0}, a1b = {0,0,0,0};
            const unsigned short* w1p = w1base + (size_t)s * 65536;
            #pragma unroll
            for (int nc = 0; nc < 16; nc += 2) {
                bf16x8 ha0 = *reinterpret_cast<const bf16x8*>(&h_lds[lo * 520 + nc * 32 + hi * 8]);
                bf16x8 ha1 = *reinterpret_cast<const bf16x8*>(&h_lds[(16 + lo) * 520 + nc * 32 + hi * 8]);
                bf16x8 hb0 = *reinterpret_cast<const bf16x8*>(&h_lds[lo * 520 + (nc + 1) * 32 + hi * 8]);
                bf16x8 hb1 = *reinterpret_cast<const bf16x8*>(&h_lds[(16 + lo) * 520 + (nc + 1) * 32 + hi * 8]);
                bf16x8 bb0 = *reinterpret_cast<const bf16x8*>(w1p + (size_t)nc * 512);
                bf16x8 bb1 = *reinterpret_cast<const bf16x8*>(w1p + (size_t)(nc + 1) * 512);
                a0a = __builtin_amdgcn_mfma_f32_16x16x32_bf16(ha0, bb0, a0a, 0, 0, 0);
                a1a = __builtin_amdgcn_mfma_f32_16x16x32_bf16(ha1, bb0, a1a, 0, 0, 0);
                a0b = __builtin_amdgcn_mfma_f32_16x16x32_bf16(hb0, bb1, a0b, 0, 0, 0);
                a1b = __builtin_amdgcn_mfma_f32_16x16x32_bf16(hb1, bb1, a1b, 0, 0, 0);
            }
            f32x4 d0 = a0a + a0b;
            f32x4 d1 = a1a + a1b;

            // r = x / (denom + eps)  (C-layout: row=hi*4+i (+16), col=w*16+lo)
            #pragma unroll
            for (int i = 0; i < 4; ++i) {
                int row0 = hi * 4 + i;
                float x0 = bf2f(x_lds[row0 * 136 + w * 16 + lo]);
                float x1 = bf2f(x_lds[(16 + row0) * 136 + w * 16 + lo]);
                float r0 = x0 / (d0[i] + 1e-20f);
                float r1 = x1 / (d1[i] + 1e-20f);
                r_lds[row0 * 136 + w * 16 + lo] = f2bf(r0);
                r_lds[(16 + row0) * 136 + w * 16 + lo] = f2bf(r1);
            }
            __syncthreads();

            // ---- Phase B: t[rows][w*64 + nt*16 + lo] += r @ W^T
            const unsigned short* w2p = w2base + (size_t)s * 65536;
            #pragma unroll
            for (int kc = 0; kc < 4; ++kc) {
                bf16x8 ra0 = *reinterpret_cast<const bf16x8*>(&r_lds[lo * 136 + kc * 32 + hi * 8]);
                bf16x8 ra1 = *reinterpret_cast<const bf16x8*>(&r_lds[(16 + lo) * 136 + kc * 32 + hi * 8]);
                const unsigned short* w2k = w2p + (size_t)kc * 16384;
                #pragma unroll
                for (int nt = 0; nt < 4; ++nt) {
                    bf16x8 bb = *reinterpret_cast<const bf16x8*>(w2k + (size_t)nt * 512);
                    tacc[0][nt] = __builtin_amdgcn_mfma_f32_16x16x32_bf16(ra0, bb, tacc[0][nt], 0, 0, 0);
                    tacc[1][nt] = __builtin_amdgcn_mfma_f32_16x16x32_bf16(ra1, bb, tacc[1][nt], 0, 0, 0);
                }
            }
            __syncthreads();
        }

        // ---- iteration boundary: h_new = normalize(h * (1 + t)), all fp32 in regs
        float p[2][4];
        #pragma unroll
        for (int m = 0; m < 2; ++m)
            #pragma unroll
            for (int i = 0; i < 4; ++i) p[m][i] = 0.f;

        #pragma unroll
        for (int m = 0; m < 2; ++m)
            #pragma unroll
            for (int nt = 0; nt < 4; ++nt)
                #pragma unroll
                for (int i = 0; i < 4; ++i) {
                    float v = h_reg[m][nt][i] * (1.f + tacc[m][nt][i]);  // EPSILON_0 = 1
                    h_reg[m][nt][i] = v;
                    p[m][i] += v;
                }
        #pragma unroll
        for (int mask = 1; mask < 16; mask <<= 1)
            #pragma unroll
            for (int m = 0; m < 2; ++m)
                #pragma unroll
                for (int i = 0; i < 4; ++i)
                    p[m][i] += __shfl_xor(p[m][i], mask, 64);
        if (lo == 0) {
            #pragma unroll
            for (int m = 0; m < 2; ++m)
                #pragma unroll
                for (int i = 0; i < 4; ++i)
                    red[w][m * 16 + hi * 4 + i] = p[m][i];
        }
        __syncthreads();
        float inv[2][4];
        #pragma unroll
        for (int m = 0; m < 2; ++m)
            #pragma unroll
            for (int i = 0; i < 4; ++i) {
                int row = m * 16 + hi * 4 + i;
                float S = 0.f;
                #pragma unroll
                for (int ww = 0; ww < 8; ++ww) S += red[ww][row];
                inv[m][i] = 1.f / (S + 1e-20f);
            }

        if (it < 4) {
            #pragma unroll
            for (int m = 0; m < 2; ++m)
                #pragma unroll
                for (int nt = 0; nt < 4; ++nt)
                    #pragma unroll
                    for (int i = 0; i < 4; ++i) {
                        int row = m * 16 + hi * 4 + i;
                        int col = w * 64 + nt * 16 + lo;
                        float hv = h_reg[m][nt][i] * inv[m][i];
                        h_reg[m][nt][i] = hv;
                        h_lds[row * 520 + col] = f2bf(hv);
                    }
            __syncthreads();
        } else {
            #pragma unroll
            for (int m = 0; m < 2; ++m)
                #pragma unroll
                for (int nt = 0; nt < 4; ++nt)
                    #pragma unroll
                    for (int i = 0; i < 4; ++i) {
                        int row = m * 16 + hi * 4 + i;
                        int col = w * 64 + nt * 16 + lo;
                        out[(size_t)(b0 + row) * 512 + col] = h_reg[m][nt][i] * inv[m][i];
                    }
        }
    }
}

extern "C" void kernel_launch(void* const* d_in, const int* in_sizes, int n_in,
                              void* d_out, int out_size, void* d_ws, size_t ws_size,
                              hipStream_t stream) {
    const float* x   = (const float*)d_in[0];   // [8192][3072]
    const float* wgt = (const float*)d_in[1];   // [512][3072]
    const float* h0  = (const float*)d_in[2];   // [512]
    float* out = (float*)d_out;

    // workspace layout (bytes): X2 bf16 50,331,648 | W1 bf16 3,145,728 | W2 bf16 3,145,728
    unsigned short* X2 = (unsigned short*)d_ws;
    unsigned short* W1 = (unsigned short*)((char*)d_ws + 50331648);
    unsigned short* W2 = (unsigned short*)((char*)d_ws + 53477376);

    prep_w<<<1536, 256, 0, stream>>>(wgt, W1, W2);
    prep_x<<<8192, 256, 0, stream>>>(x, X2);
    nnmf_main<<<256, 512, 0, stream>>>(X2, W1, W2, h0, out);
}

// Round 3
// 569.698 us; speedup vs baseline: 1.7469x; 1.7469x over previous
//
#include <hip/hip_runtime.h>

// NNMF fused kernel: B=8192, NIN=3072, NOUT=512, 5 iterations.
// R2: software-pipelined K-loop. W1/W2 MFMA operands prefetched into VGPRs with
// plain global loads (survive barriers; waits are fine-grained vmcnt at use).
// 2 barriers/step; x tile prefetched one step ahead; divides -> v_rcp_f32.

#define NIN 3072
#define NOUT 512
#define BT 32

using bf16x8 = __attribute__((ext_vector_type(8))) short;
using f32x4  = __attribute__((ext_vector_type(4))) float;

__device__ __forceinline__ unsigned short f2bf(float f) {
    unsigned int u = __builtin_bit_cast(unsigned int, f);
    return (unsigned short)((u + 0x7fffu + ((u >> 16) & 1u)) >> 16);  // RNE
}
__device__ __forceinline__ float bf2f(unsigned short s) {
    unsigned int u = ((unsigned int)s) << 16;
    return __builtin_bit_cast(float, u);
}

// ---------------------------------------------------------------------------
// prep_w: shuffle W (fp32 [512][3072]) into MFMA-frag-native bf16 buffers.
// W2 (for t = r @ W^T, contract over k): frag (kcg in [0,96), nt in [0,32)):
//   W2[((kcg*32+nt)*64 + l)*8 + j] = W[nt*16 + (l&15)][kcg*32 + (l>>4)*8 + j]
// W1 (for denom = h @ W, contract over n): frag (ktg in [0,192), nc in [0,16)):
//   W1[((ktg*16+nc)*64 + l)*8 + j] = W[nc*32 + (l>>4)*8 + j][ktg*16 + (l&15)]
// ---------------------------------------------------------------------------
__global__ void prep_w(const float* __restrict__ W,
                       unsigned short* __restrict__ W1,
                       unsigned short* __restrict__ W2) {
    int t = blockIdx.x * 256 + threadIdx.x;   // 0 .. 393215
    const int half = 196608;
    if (t < half) {
        int f = t >> 6, l = t & 63;
        int kcg = f >> 5, nt = f & 31;
        int n = nt * 16 + (l & 15);
        int k = kcg * 32 + ((l >> 4) << 3);
        unsigned short* dst = W2 + (size_t)t * 8;
        const float* src = W + (size_t)n * NIN + k;
        #pragma unroll
        for (int j = 0; j < 8; ++j) dst[j] = f2bf(src[j]);
    } else {
        int u = t - half;
        int f = u >> 6, l = u & 63;
        int ktg = f >> 4, nc = f & 15;
        int k = ktg * 16 + (l & 15);
        int nb = nc * 32 + ((l >> 4) << 3);
        unsigned short* dst = W1 + (size_t)u * 8;
        #pragma unroll
        for (int j = 0; j < 8; ++j) dst[j] = f2bf(W[(size_t)(nb + j) * NIN + k]);
    }
}

// ---------------------------------------------------------------------------
// prep_x: per-row normalize x and store bf16.
// ---------------------------------------------------------------------------
__global__ void prep_x(const float* __restrict__ x, unsigned short* __restrict__ X2) {
    int b = blockIdx.x;
    int t = threadIdx.x;                      // 256 threads
    const float4* r4 = reinterpret_cast<const float4*>(x + (size_t)b * NIN);
    float s = 0.f;
    float4 v0 = r4[t], v1 = r4[t + 256], v2 = r4[t + 512];
    s = v0.x + v0.y + v0.z + v0.w + v1.x + v1.y + v1.z + v1.w + v2.x + v2.y + v2.z + v2.w;
    #pragma unroll
    for (int off = 32; off > 0; off >>= 1) s += __shfl_down(s, off, 64);
    __shared__ float wsum[4];
    int w = t >> 6, l = t & 63;
    if (l == 0) wsum[w] = s;
    __syncthreads();
    float inv = 1.0f / (wsum[0] + wsum[1] + wsum[2] + wsum[3] + 1e-20f);
    unsigned short* orow = X2 + (size_t)b * NIN;
    #pragma unroll
    for (int c = 0; c < 3; ++c) {
        float4 v = (c == 0) ? v0 : (c == 1) ? v1 : v2;
        ushort4 o;
        o.x = f2bf(v.x * inv); o.y = f2bf(v.y * inv);
        o.z = f2bf(v.z * inv); o.w = f2bf(v.w * inv);
        *reinterpret_cast<ushort4*>(orow + (t + c * 256) * 4) = o;
    }
}

// ---------------------------------------------------------------------------
// Main fused kernel. 256 blocks x 512 threads (8 waves), 32 rows/block.
// Pipelined step:
//   [top] issue W2[s] -> w2buf (regs)           (cover: Phase A)
//   Phase A: denom MFMAs, W1 operands ALREADY in w1buf regs
//   r-phase (rcp), write r_lds
//   barrier A
//   Phase B 1st half; reload w1buf = W1[s+1]; Phase B 2nd half
//   store prefetched x[s+1] -> x_lds; prefetch x[s+2]
//   barrier B
// ---------------------------------------------------------------------------
__global__ __launch_bounds__(512, 2) void nnmf_main(
    const unsigned short* __restrict__ X2,
    const unsigned short* __restrict__ W1,
    const unsigned short* __restrict__ W2,
    const float* __restrict__ h_init,
    float* __restrict__ out)
{
    __shared__ unsigned short h_lds[32 * 520];   // pad 512->520
    __shared__ unsigned short x_lds[32 * 136];   // pad 128->136
    __shared__ unsigned short r_lds[32 * 136];
    __shared__ float red[8][32];

    const int tid = threadIdx.x;
    const int w  = tid >> 6;        // wave 0..7
    const int l  = tid & 63;
    const int lo = l & 15;
    const int hi = l >> 4;          // 0..3
    const int b0 = blockIdx.x * BT;

    // init h_lds from h_initial (same value for every row)
    for (int idx = tid; idx < 32 * 512; idx += 512) {
        int r = idx >> 9, c = idx & 511;
        h_lds[r * 520 + c] = f2bf(h_init[c]);
    }

    // fp32 h in registers, C-layout: row=m*16+hi*4+i, col=w*64+nt*16+lo
    float h_reg[2][4][4];
    #pragma unroll
    for (int nt = 0; nt < 4; ++nt) {
        float hv = h_init[w * 64 + nt * 16 + lo];
        #pragma unroll
        for (int m = 0; m < 2; ++m)
            #pragma unroll
            for (int i = 0; i < 4; ++i)
                h_reg[m][nt][i] = hv;
    }

    // x staging: thread -> (row, 16B chunk)
    const int xrow = tid >> 4, xcc = tid & 15;
    const uint4* xg = reinterpret_cast<const uint4*>(X2 + (size_t)(b0 + xrow) * NIN + xcc * 8);
    unsigned short* xdst = &x_lds[xrow * 136 + xcc * 8];

    // W frag base pointers (element offsets)
    const unsigned short* w1base = W1 + ((size_t)(w * 16) * 64 + l) * 8;  // +s*65536, +nc*512
    const unsigned short* w2base = W2 + ((size_t)(w * 4) * 64 + l) * 8;   // +s*65536, +kc*16384, +nt*512

    // ---- prime the pipeline: x[0] -> LDS, x[1] -> reg, W1[0] -> regs
    *reinterpret_cast<uint4*>(xdst) = xg[0];
    uint4 xnext = xg[16];
    bf16x8 w1buf[16];
    #pragma unroll
    for (int nc = 0; nc < 16; ++nc)
        w1buf[nc] = *reinterpret_cast<const bf16x8*>(w1base + (size_t)nc * 512);
    __syncthreads();

    f32x4 tacc[2][4];

    for (int it = 0; it < 5; ++it) {
        #pragma unroll
        for (int m = 0; m < 2; ++m)
            #pragma unroll
            for (int nt = 0; nt < 4; ++nt)
                tacc[m][nt] = (f32x4){0.f, 0.f, 0.f, 0.f};

        for (int s = 0; s < 24; ++s) {
            const int sn  = (s + 1 == 24) ? 0 : s + 1;
            const int sn2 = (s + 2 >= 24) ? (s + 2 - 24) : s + 2;

            // ---- issue W2[s] loads (consumed in Phase B; covered by Phase A)
            bf16x8 w2buf[16];
            {
                const unsigned short* w2p = w2base + (size_t)s * 65536;
                #pragma unroll
                for (int kc = 0; kc < 4; ++kc)
                    #pragma unroll
                    for (int nt = 0; nt < 4; ++nt)
                        w2buf[kc * 4 + nt] = *reinterpret_cast<const bf16x8*>(
                            w2p + (size_t)kc * 16384 + nt * 512);
            }

            // ---- Phase A: denom tiles, W1 operands already register-resident
            f32x4 a0a = {0,0,0,0}, a0b = {0,0,0,0}, a1a = {0,0,0,0}, a1b = {0,0,0,0};
            #pragma unroll
            for (int nc = 0; nc < 16; nc += 2) {
                bf16x8 ha0 = *reinterpret_cast<const bf16x8*>(&h_lds[lo * 520 + nc * 32 + hi * 8]);
                bf16x8 ha1 = *reinterpret_cast<const bf16x8*>(&h_lds[(16 + lo) * 520 + nc * 32 + hi * 8]);
                bf16x8 hb0 = *reinterpret_cast<const bf16x8*>(&h_lds[lo * 520 + (nc + 1) * 32 + hi * 8]);
                bf16x8 hb1 = *reinterpret_cast<const bf16x8*>(&h_lds[(16 + lo) * 520 + (nc + 1) * 32 + hi * 8]);
                a0a = __builtin_amdgcn_mfma_f32_16x16x32_bf16(ha0, w1buf[nc],     a0a, 0, 0, 0);
                a1a = __builtin_amdgcn_mfma_f32_16x16x32_bf16(ha1, w1buf[nc],     a1a, 0, 0, 0);
                a0b = __builtin_amdgcn_mfma_f32_16x16x32_bf16(hb0, w1buf[nc + 1], a0b, 0, 0, 0);
                a1b = __builtin_amdgcn_mfma_f32_16x16x32_bf16(hb1, w1buf[nc + 1], a1b, 0, 0, 0);
            }
            f32x4 d0 = a0a + a0b;
            f32x4 d1 = a1a + a1b;

            // ---- r = x * rcp(denom + eps)  (C-layout)
            #pragma unroll
            for (int i = 0; i < 4; ++i) {
                int row0 = hi * 4 + i;
                float x0 = bf2f(x_lds[row0 * 136 + w * 16 + lo]);
                float x1 = bf2f(x_lds[(16 + row0) * 136 + w * 16 + lo]);
                float r0 = x0 * __builtin_amdgcn_rcpf(d0[i] + 1e-20f);
                float r1 = x1 * __builtin_amdgcn_rcpf(d1[i] + 1e-20f);
                r_lds[row0 * 136 + w * 16 + lo] = f2bf(r0);
                r_lds[(16 + row0) * 136 + w * 16 + lo] = f2bf(r1);
            }
            __syncthreads();   // barrier A

            // ---- Phase B 1st half (kc 0,1), w2buf register-resident
            #pragma unroll
            for (int kc = 0; kc < 2; ++kc) {
                bf16x8 ra0 = *reinterpret_cast<const bf16x8*>(&r_lds[lo * 136 + kc * 32 + hi * 8]);
                bf16x8 ra1 = *reinterpret_cast<const bf16x8*>(&r_lds[(16 + lo) * 136 + kc * 32 + hi * 8]);
                #pragma unroll
                for (int nt = 0; nt < 4; ++nt) {
                    tacc[0][nt] = __builtin_amdgcn_mfma_f32_16x16x32_bf16(ra0, w2buf[kc * 4 + nt], tacc[0][nt], 0, 0, 0);
                    tacc[1][nt] = __builtin_amdgcn_mfma_f32_16x16x32_bf16(ra1, w2buf[kc * 4 + nt], tacc[1][nt], 0, 0, 0);
                }
            }

            // ---- reload w1buf with W1[s+1] (Phase A done with it; WAR keeps order)
            {
                const unsigned short* w1p = w1base + (size_t)sn * 65536;
                #pragma unroll
                for (int nc = 0; nc < 16; ++nc)
                    w1buf[nc] = *reinterpret_cast<const bf16x8*>(w1p + (size_t)nc * 512);
            }

            // ---- Phase B 2nd half (kc 2,3)
            #pragma unroll
            for (int kc = 2; kc < 4; ++kc) {
                bf16x8 ra0 = *reinterpret_cast<const bf16x8*>(&r_lds[lo * 136 + kc * 32 + hi * 8]);
                bf16x8 ra1 = *reinterpret_cast<const bf16x8*>(&r_lds[(16 + lo) * 136 + kc * 32 + hi * 8]);
                #pragma unroll
                for (int nt = 0; nt < 4; ++nt) {
                    tacc[0][nt] = __builtin_amdgcn_mfma_f32_16x16x32_bf16(ra0, w2buf[kc * 4 + nt], tacc[0][nt], 0, 0, 0);
                    tacc[1][nt] = __builtin_amdgcn_mfma_f32_16x16x32_bf16(ra1, w2buf[kc * 4 + nt], tacc[1][nt], 0, 0, 0);
                }
            }

            // ---- stage x[s+1] (r-phase reads of x[s] all happened before barrier A)
            *reinterpret_cast<uint4*>(xdst) = xnext;
            xnext = xg[sn2 * 16];
            __syncthreads();   // barrier B
        }

        // ---- iteration boundary: h_new = normalize(h * (1 + t)), fp32 in regs
        float p[2][4];
        #pragma unroll
        for (int m = 0; m < 2; ++m)
            #pragma unroll
            for (int i = 0; i < 4; ++i) p[m][i] = 0.f;

        #pragma unroll
        for (int m = 0; m < 2; ++m)
            #pragma unroll
            for (int nt = 0; nt < 4; ++nt)
                #pragma unroll
                for (int i = 0; i < 4; ++i) {
                    float v = h_reg[m][nt][i] * (1.f + tacc[m][nt][i]);  // EPSILON_0 = 1
                    h_reg[m][nt][i] = v;
                    p[m][i] += v;
                }
        #pragma unroll
        for (int mask = 1; mask < 16; mask <<= 1)
            #pragma unroll
            for (int m = 0; m < 2; ++m)
                #pragma unroll
                for (int i = 0; i < 4; ++i)
                    p[m][i] += __shfl_xor(p[m][i], mask, 64);
        if (lo == 0) {
            #pragma unroll
            for (int m = 0; m < 2; ++m)
                #pragma unroll
                for (int i = 0; i < 4; ++i)
                    red[w][m * 16 + hi * 4 + i] = p[m][i];
        }
        __syncthreads();
        float inv[2][4];
        #pragma unroll
        for (int m = 0; m < 2; ++m)
            #pragma unroll
            for (int i = 0; i < 4; ++i) {
                int row = m * 16 + hi * 4 + i;
                float S = 0.f;
                #pragma unroll
                for (int ww = 0; ww < 8; ++ww) S += red[ww][row];
                inv[m][i] = 1.f / (S + 1e-20f);
            }

        if (it < 4) {
            #pragma unroll
            for (int m = 0; m < 2; ++m)
                #pragma unroll
                for (int nt = 0; nt < 4; ++nt)
                    #pragma unroll
                    for (int i = 0; i < 4; ++i) {
                        int row = m * 16 + hi * 4 + i;
                        int col = w * 64 + nt * 16 + lo;
                        float hv = h_reg[m][nt][i] * inv[m][i];
                        h_reg[m][nt][i] = hv;
                        h_lds[row * 520 + col] = f2bf(hv);
                    }
            __syncthreads();
        } else {
            #pragma unroll
            for (int m = 0; m < 2; ++m)
                #pragma unroll
                for (int nt = 0; nt < 4; ++nt)
                    #pragma unroll
                    for (int i = 0; i < 4; ++i) {
                        int row = m * 16 + hi * 4 + i;
                        int col = w * 64 + nt * 16 + lo;
                        out[(size_t)(b0 + row) * 512 + col] = h_reg[m][nt][i] * inv[m][i];
                    }
        }
    }
}

extern "C" void kernel_launch(void* const* d_in, const int* in_sizes, int n_in,
                              void* d_out, int out_size, void* d_ws, size_t ws_size,
                              hipStream_t stream) {
    const float* x   = (const float*)d_in[0];   // [8192][3072]
    const float* wgt = (const float*)d_in[1];   // [512][3072]
    const float* h0  = (const float*)d_in[2];   // [512]
    float* out = (float*)d_out;

    // workspace layout (bytes): X2 bf16 50,331,648 | W1 bf16 3,145,728 | W2 bf16 3,145,728
    unsigned short* X2 = (unsigned short*)d_ws;
    unsigned short* W1 = (unsigned short*)((char*)d_ws + 50331648);
    unsigned short* W2 = (unsigned short*)((char*)d_ws + 53477376);

    prep_w<<<1536, 256, 0, stream>>>(wgt, W1, W2);
    prep_x<<<8192, 256, 0, stream>>>(x, X2);
    nnmf_main<<<256, 512, 0, stream>>>(X2, W1, W2, h0, out);
}